// Round 2
// baseline (3390.928 us; speedup 1.0000x reference)
//
#include <hip/hip_runtime.h>
#include <hip/hip_cooperative_groups.h>

namespace cg = cooperative_groups;

#define NPTS 2048
#define NB 4
#define NITS 50
#define TOLC 1e-3f
#define EPSC 0.1f
#define INV_EPS 10.0f
#define LAC (-1.3862943611198906f)  /* log(1/4) */
#define L2E 1.4426950408889634f
#define LN2C 0.6931471805599453f
#define KS (L2E*2.0f*INV_EPS)

/* workspace layout (float offsets). First ZERO_FLOATS are zero-initialized. */
#define OFF_A 0            /* [8][2048] column-side potentials */
#define OFF_B 16384        /* [8][2048] row-side potentials    */
#define OFF_ERR 32768      /* [50][8][2] |delta| sums          */
#define OFF_COST 33568     /* [8] raw transp*C sums            */
#define OFF_CHAM 33576     /* [1] chamfer                      */
#define ZERO_FLOATS 33577
#define OFF_RNP 33600      /* [4][2048] ||pred||^2             */
#define OFF_RNG 41792      /* [4][2048] ||gt||^2               */
#define OFF_SVP 50000      /* [4][2048] float4 scaled preds    */
#define OFF_SVG 82768      /* [4][2048] float4 scaled gts      */

__device__ __forceinline__ float wsum(float v) {
#pragma unroll
  for (int o = 32; o; o >>= 1) v += __shfl_xor(v, o, 64);
  return v;
}

__global__ void prep_k(const float* __restrict__ preds, const float* __restrict__ gts,
                       float* __restrict__ ws) {
  int idx = blockIdx.x * 256 + threadIdx.x;
  if (idx >= 2 * NB * NPTS) return;
  int side = idx >> 13;                 /* 0: preds, 1: gts */
  int k = idx & (NB * NPTS - 1);
  const float* src = side ? gts : preds;
  float x = src[k*3+0], y = src[k*3+1], z = src[k*3+2];
  float rn = x*x + y*y + z*z;
  (ws + (side ? OFF_RNG : OFF_RNP))[k] = rn;
  float4* sv = reinterpret_cast<float4*>(ws + (side ? OFF_SVG : OFF_SVP));
  sv[k] = make_float4(KS*x, KS*y, KS*z, -L2E*rn*INV_EPS);
}

/* dir 0: rows=gts cols=preds (loss_2); dir 1: rows=preds cols=gts (loss_1). */
__global__ __launch_bounds__(256) void chamfer_k(const float* __restrict__ preds,
                                                 const float* __restrict__ gts,
                                                 float* __restrict__ ws) {
  __shared__ float4 colv[NPTS];
  int dir = blockIdx.x >> 5;
  int b = (blockIdx.x >> 3) & 3;
  int chunk = blockIdx.x & 7;
  const float* rowP = dir ? preds : gts;
  const float* colP = dir ? gts : preds;
  const float* rowN = ws + (dir ? OFF_RNP : OFF_RNG) + b * NPTS;
  const float* colN = ws + (dir ? OFF_RNG : OFF_RNP) + b * NPTS;
  for (int c = threadIdx.x; c < NPTS; c += 256) {
    const float* p = colP + (b * NPTS + c) * 3;
    colv[c] = make_float4(p[0], p[1], p[2], colN[c]);
  }
  __syncthreads();
  int r = chunk * 256 + threadIdx.x;
  const float* p = rowP + (b * NPTS + r) * 3;
  float nx = -2.f*p[0], ny = -2.f*p[1], nz = -2.f*p[2];
  float mn = 1e30f;
  for (int c = 0; c < NPTS; ++c) {
    float4 v = colv[c];
    float t = fmaf(nx, v.x, fmaf(ny, v.y, fmaf(nz, v.z, v.w)));
    mn = fminf(mn, t);
  }
  mn += rowN[r];
  mn = wsum(mn);
  if ((threadIdx.x & 63) == 0) atomicAdd(ws + OFF_CHAM, mn * (1.0f/8192.0f));
}

/* One Sinkhorn half-update for one problem, one block's 64 output slots.
   sv/sPot: the side being reduced over (staged to LDS); o*: the output side
   (potential updated in place; safe: each output owned by exactly one block,
   readers of the fresh values only run after the caller's grid.sync()). */
__device__ __forceinline__ void half_update(const float4* __restrict__ sv,
    const float* __restrict__ sPot, const float* __restrict__ oPts,
    const float* __restrict__ oNrm, float* __restrict__ oPot,
    float* __restrict__ errSlot, int blk, int tid,
    float4* rowv, float (*comb)[64]) {
  for (int i = tid; i < NPTS; i += 1024) {
    float4 v = sv[i];
    v.w += L2E * sPot[i];
    rowv[i] = v;
  }
  __syncthreads();
  const int wave = tid >> 6, lane = tid & 63;
  const int ih = wave >> 3, jq = wave & 7;
  const int o0 = blk * 64 + jq * 8;
  float y0[8], y1[8], y2[8], S[8], s[8];
#pragma unroll
  for (int q = 0; q < 8; ++q) {
    int o = o0 + q;
    y0[q] = oPts[o*3+0]; y1[q] = oPts[o*3+1]; y2[q] = oPts[o*3+2];
    float c = LAC - oNrm[o] * INV_EPS;
    S[q] = L2E * (-oPot[o] - c);   /* base-2 shift from previous potential */
    s[q] = 0.f;
  }
  const float4* basep = rowv + ih * 1024;
#pragma unroll 2
  for (int stp = 0; stp < 16; ++stp) {
    float4 v = basep[stp * 64 + lane];
#pragma unroll
    for (int q = 0; q < 8; ++q) {
      float m = v.w - S[q];
      m = fmaf(v.x, y0[q], m);
      m = fmaf(v.y, y1[q], m);
      m = fmaf(v.z, y2[q], m);
      s[q] += __builtin_amdgcn_exp2f(m);
    }
  }
#pragma unroll
  for (int q = 0; q < 8; ++q) s[q] = wsum(s[q]);
  if (lane == 0) {
#pragma unroll
    for (int q = 0; q < 8; ++q) comb[ih][jq * 8 + q] = s[q];
  }
  __syncthreads();
  if (tid < 64) {
    int o = blk * 64 + tid;
    float stot = fmaxf(comb[0][tid] + comb[1][tid], 1e-38f);
    float c = LAC - oNrm[o] * INV_EPS;
    float Sv = L2E * (-oPot[o] - c);
    float nv = -c - LN2C * (__builtin_amdgcn_logf(stot) + Sv);
    float d = fabsf(nv - oPot[o]);
    oPot[o] = nv;
    d = wsum(d);
    if (tid == 0) atomicAdd(errSlot, d);
  }
  __syncthreads();
}

__global__ __launch_bounds__(1024, 4) void sink_k(const float* __restrict__ preds,
    const float* __restrict__ gts, float* __restrict__ ws, float* __restrict__ out) {
  cg::grid_group grid = cg::this_grid();
  __shared__ float4 rowv[NPTS];
  __shared__ float comb[2][64];
  __shared__ float bst[NPTS];
  const int p = blockIdx.x >> 5;       /* problem 0..7: 0-3 = C(gts,preds), 4-7 = C(preds,preds) */
  const int blk = blockIdx.x & 31;
  const int b = p & 3;
  const bool fs = (p < 4);
  const int tid = threadIdx.x;

  const float* colPts = preds + b * NPTS * 3;
  const float* colNrm = ws + OFF_RNP + b * NPTS;
  const float4* colSv = reinterpret_cast<const float4*>(ws + OFF_SVP) + b * NPTS;
  const float* rowPts = fs ? gts + b * NPTS * 3 : colPts;
  const float* rowNrm = fs ? ws + OFF_RNG + b * NPTS : colNrm;
  const float4* rowSv = fs ? reinterpret_cast<const float4*>(ws + OFF_SVG) + b * NPTS : colSv;
  float* Ap = ws + OFF_A + p * NPTS;   /* column-side potential (reference A) */
  float* Bp = ws + OFF_B + p * NPTS;   /* row-side potential   (reference B) */
  float* err = ws + OFF_ERR;

  for (int it = 0; it < NITS; ++it) {
    /* uniform activity decision, mirroring the reference while-loop cond */
    bool actg[2];
    if (it == 0) { actg[0] = actg[1] = true; }
    else {
#pragma unroll
      for (int g = 0; g < 2; ++g) {
        float ae = 0.f, be = 0.f;
#pragma unroll
        for (int q = 0; q < 4; ++q) {
          ae = fmaxf(ae, err[((it-1)*8 + g*4 + q)*2 + 0]);
          be = fmaxf(be, err[((it-1)*8 + g*4 + q)*2 + 1]);
        }
        const float sc = EPSC / (float)NPTS;
        actg[g] = (sc*ae >= TOLC) || (sc*be >= TOLC);
      }
    }
    if (!actg[0] && !actg[1]) break;
    bool mine = actg[p >> 2];
    /* A-half: reduce over rows (B-potential), update column potentials */
    if (mine) half_update(rowSv, Bp, colPts, colNrm, Ap,
                          err + ((it*8+p)*2+0), blk, tid, rowv, comb);
    grid.sync();
    /* B-half: reduce over cols (fresh A), update row potentials */
    if (mine) half_update(colSv, Ap, rowPts, rowNrm, Bp,
                          err + ((it*8+p)*2+1), blk, tid, rowv, comb);
    grid.sync();
  }

  /* cost = sum_ij exp(A_j + B_i - C/eps) * C_ij  (scale 1/(n*m) at the end) */
  {
    for (int i = tid; i < NPTS; i += 1024) {
      float4 v = rowSv[i];
      float bv = Bp[i];
      v.w += L2E * bv;
      rowv[i] = v;
      bst[i] = EPSC * bv;
    }
    __syncthreads();
    const int wave = tid >> 6, lane = tid & 63;
    const int ih = wave >> 3, jq = wave & 7;
    const int j0 = blk * 64 + jq * 8;
    float y0[8], y1[8], y2[8], Q[8], EA[8];
#pragma unroll
    for (int q = 0; q < 8; ++q) {
      int j = j0 + q;
      y0[q] = colPts[j*3+0]; y1[q] = colPts[j*3+1]; y2[q] = colPts[j*3+2];
      float aj = Ap[j];
      Q[q] = L2E * (aj - colNrm[j] * INV_EPS);
      EA[q] = EPSC * aj;
    }
    float acc = 0.f;
    const float4* basep = rowv + ih * 1024;
#pragma unroll 2
    for (int stp = 0; stp < 16; ++stp) {
      int il = stp * 64 + lane;
      float4 v = basep[il];
      float eb = bst[ih * 1024 + il];
#pragma unroll
      for (int q = 0; q < 8; ++q) {
        float m = v.w + Q[q];
        m = fmaf(v.x, y0[q], m);
        m = fmaf(v.y, y1[q], m);
        m = fmaf(v.z, y2[q], m);
        float e = __builtin_amdgcn_exp2f(m);           /* transp * (n*m) */
        float Cv = fmaf(-(EPSC*LN2C), m, eb + EA[q]);  /* C = eps*(A+B - m*ln2) */
        acc = fmaf(e, Cv, acc);
      }
    }
    acc = wsum(acc);
    if (lane == 0) atomicAdd(ws + OFF_COST + p, acc);
  }
  grid.sync();
  if (blockIdx.x == 0 && tid < 5) {
    if (tid < 4)
      out[tid] = (ws[OFF_COST + tid] - 0.5f * ws[OFF_COST + 4 + tid]) *
                 (1.0f / ((float)NPTS * (float)NPTS));
    else
      out[4] = ws[OFF_CHAM];
  }
}

extern "C" void kernel_launch(void* const* d_in, const int* in_sizes, int n_in,
                              void* d_out, int out_size, void* d_ws, size_t ws_size,
                              hipStream_t stream) {
  const float* preds = (const float*)d_in[0];
  const float* gts   = (const float*)d_in[1];
  float* wsf  = (float*)d_ws;
  float* outf = (float*)d_out;

  hipMemsetAsync(d_ws, 0, ZERO_FLOATS * sizeof(float), stream);
  prep_k<<<64, 256, 0, stream>>>(preds, gts, wsf);
  chamfer_k<<<64, 256, 0, stream>>>(preds, gts, wsf);

  void* args[] = { (void*)&preds, (void*)&gts, (void*)&wsf, (void*)&outf };
  hipLaunchCooperativeKernel((void*)sink_k, dim3(256), dim3(1024), args, 0, stream);
}

// Round 6
// 2319.776 us; speedup vs baseline: 1.4617x; 1.4617x over previous
//
#include <hip/hip_runtime.h>

#define NPTS 2048
#define NB 4
#define NITS 50
#define TOLC 1e-3f
#define EPSC 0.1f
#define INV_EPS 10.0f
#define LAC (-1.3862943611198906f)  /* log(1/4) */
#define L2E 1.4426950408889634f
#define LN2C 0.6931471805599453f
#define KS (L2E*2.0f*INV_EPS)

/* workspace layout (float offsets). First ZERO_FLOATS are zero-initialized. */
#define OFF_A 0            /* [8][2048] column-side potentials */
#define OFF_B 16384        /* [8][2048] row-side potentials    */
#define OFF_ERR 32768      /* [50][8][2] |delta| sums          */
#define OFF_COST 33568     /* [8] raw transp*C sums            */
#define OFF_CHAM 33576     /* [1] chamfer                      */
#define OFF_BARC 33577     /* [2] unsigned barrier arrival counters (per group) */
#define OFF_DONE 33579     /* [1] unsigned done counter */
#define ZERO_FLOATS 33580
#define OFF_RNP 33600      /* [4][2048] ||pred||^2             */
#define OFF_RNG 41792      /* [4][2048] ||gt||^2               */
#define OFF_SVP 50000      /* [4][2048] float4 scaled preds    */
#define OFF_SVG 82768      /* [4][2048] float4 scaled gts      */

__device__ __forceinline__ float wsum(float v) {
#pragma unroll
  for (int o = 32; o; o >>= 1) v += __shfl_xor(v, o, 64);
  return v;
}

/* agent-scope (device) atomic load/store: write-around the per-XCD L2s so
   cross-block potential/err traffic always hits the coherence point. */
__device__ __forceinline__ float aload(const float* p) {
  return __hip_atomic_load(p, __ATOMIC_RELAXED, __HIP_MEMORY_SCOPE_AGENT);
}
__device__ __forceinline__ void astore(float* p, float v) {
  __hip_atomic_store(p, v, __ATOMIC_RELAXED, __HIP_MEMORY_SCOPE_AGENT);
}

/* software barrier over a block-group: monotonic arrival counter, tid-0 spins.
   ~2-4us vs ~29us for cg::grid.sync() (measured round 2). */
__device__ __forceinline__ void gbar(unsigned* c, unsigned target) {
  __syncthreads();
  if (threadIdx.x == 0) {
    __threadfence();   /* release my block's global writes */
    __hip_atomic_fetch_add(c, 1u, __ATOMIC_RELAXED, __HIP_MEMORY_SCOPE_AGENT);
    while (__hip_atomic_load(c, __ATOMIC_RELAXED, __HIP_MEMORY_SCOPE_AGENT) < target)
      __builtin_amdgcn_s_sleep(1);
    __threadfence();   /* acquire remote writes */
  }
  __syncthreads();
}

__global__ void prep_k(const float* __restrict__ preds, const float* __restrict__ gts,
                       float* __restrict__ ws) {
  int idx = blockIdx.x * 256 + threadIdx.x;
  if (idx >= 2 * NB * NPTS) return;
  int side = idx >> 13;                 /* 0: preds, 1: gts */
  int k = idx & (NB * NPTS - 1);
  const float* src = side ? gts : preds;
  float x = src[k*3+0], y = src[k*3+1], z = src[k*3+2];
  float rn = x*x + y*y + z*z;
  (ws + (side ? OFF_RNG : OFF_RNP))[k] = rn;
  float4* sv = reinterpret_cast<float4*>(ws + (side ? OFF_SVG : OFF_SVP));
  sv[k] = make_float4(KS*x, KS*y, KS*z, -L2E*rn*INV_EPS);
}

/* dir 0: rows=gts cols=preds (loss_2); dir 1: rows=preds cols=gts (loss_1). */
__global__ __launch_bounds__(256) void chamfer_k(const float* __restrict__ preds,
                                                 const float* __restrict__ gts,
                                                 float* __restrict__ ws) {
  __shared__ float4 colv[NPTS];
  int dir = blockIdx.x >> 5;
  int b = (blockIdx.x >> 3) & 3;
  int chunk = blockIdx.x & 7;
  const float* rowP = dir ? preds : gts;
  const float* colP = dir ? gts : preds;
  const float* rowN = ws + (dir ? OFF_RNP : OFF_RNG) + b * NPTS;
  const float* colN = ws + (dir ? OFF_RNG : OFF_RNP) + b * NPTS;
  for (int c = threadIdx.x; c < NPTS; c += 256) {
    const float* p = colP + (b * NPTS + c) * 3;
    colv[c] = make_float4(p[0], p[1], p[2], colN[c]);
  }
  __syncthreads();
  int r = chunk * 256 + threadIdx.x;
  const float* p = rowP + (b * NPTS + r) * 3;
  float nx = -2.f*p[0], ny = -2.f*p[1], nz = -2.f*p[2];
  float mn = 1e30f;
  for (int c = 0; c < NPTS; ++c) {
    float4 v = colv[c];
    float t = fmaf(nx, v.x, fmaf(ny, v.y, fmaf(nz, v.z, v.w)));
    mn = fminf(mn, t);
  }
  mn += rowN[r];
  mn = wsum(mn);
  if ((threadIdx.x & 63) == 0) atomicAdd(ws + OFF_CHAM, mn * (1.0f/8192.0f));
}

/* One Sinkhorn half-update for one problem, one block's 64 output slots. */
__device__ __forceinline__ void half_update(const float4* __restrict__ sv,
    const float* __restrict__ sPot, const float* __restrict__ oPts,
    const float* __restrict__ oNrm, float* __restrict__ oPot,
    float* __restrict__ errSlot, int blk, int tid,
    float4* rowv, float (*comb)[64]) {
  for (int i = tid; i < NPTS; i += 1024) {
    float4 v = sv[i];
    v.w += L2E * aload(&sPot[i]);
    rowv[i] = v;
  }
  __syncthreads();
  const int wave = tid >> 6, lane = tid & 63;
  const int ih = wave >> 3, jq = wave & 7;
  const int o0 = blk * 64 + jq * 8;
  float y0[8], y1[8], y2[8], S[8], s[8];
#pragma unroll
  for (int q = 0; q < 8; ++q) {
    int o = o0 + q;
    y0[q] = oPts[o*3+0]; y1[q] = oPts[o*3+1]; y2[q] = oPts[o*3+2];
    float c = LAC - oNrm[o] * INV_EPS;
    S[q] = L2E * (-aload(&oPot[o]) - c);   /* base-2 shift from previous potential */
    s[q] = 0.f;
  }
  const float4* basep = rowv + ih * 1024;
#pragma unroll 2
  for (int stp = 0; stp < 16; ++stp) {
    float4 v = basep[stp * 64 + lane];
#pragma unroll
    for (int q = 0; q < 8; ++q) {
      float m = v.w - S[q];
      m = fmaf(v.x, y0[q], m);
      m = fmaf(v.y, y1[q], m);
      m = fmaf(v.z, y2[q], m);
      s[q] += __builtin_amdgcn_exp2f(m);
    }
  }
#pragma unroll
  for (int q = 0; q < 8; ++q) s[q] = wsum(s[q]);
  if (lane == 0) {
#pragma unroll
    for (int q = 0; q < 8; ++q) comb[ih][jq * 8 + q] = s[q];
  }
  __syncthreads();
  if (tid < 64) {
    int o = blk * 64 + tid;
    float stot = fmaxf(comb[0][tid] + comb[1][tid], 1e-38f);
    float c = LAC - oNrm[o] * INV_EPS;
    float Sv = L2E * (-aload(&oPot[o]) - c);
    float nv = -c - LN2C * (__builtin_amdgcn_logf(stot) + Sv);
    float d = fabsf(nv - aload(&oPot[o]));
    astore(&oPot[o], nv);
    d = wsum(d);
    if (tid == 0) atomicAdd(errSlot, d);
  }
  __syncthreads();
}

__global__ __launch_bounds__(1024, 4) void sink_k(const float* __restrict__ preds,
    const float* __restrict__ gts, float* __restrict__ ws, float* __restrict__ out) {
  __shared__ float4 rowv[NPTS];
  __shared__ float comb[2][64];
  __shared__ float bst[NPTS];
  /* p = blockIdx&7: with round-robin XCD dispatch this clusters each problem
     on one XCD (perf heuristic only; correctness doesn't depend on it). */
  const int p = blockIdx.x & 7;        /* 0-3 = C(gts,preds) group 0, 4-7 = C(preds,preds) group 1 */
  const int blk = blockIdx.x >> 3;     /* 0..31 */
  const int b = p & 3;
  const int g = p >> 2;
  const bool fs = (g == 0);
  const int tid = threadIdx.x;

  const float* colPts = preds + b * NPTS * 3;
  const float* colNrm = ws + OFF_RNP + b * NPTS;
  const float4* colSv = reinterpret_cast<const float4*>(ws + OFF_SVP) + b * NPTS;
  const float* rowPts = fs ? gts + b * NPTS * 3 : colPts;
  const float* rowNrm = fs ? ws + OFF_RNG + b * NPTS : colNrm;
  const float4* rowSv = fs ? reinterpret_cast<const float4*>(ws + OFF_SVG) + b * NPTS : colSv;
  float* Ap = ws + OFF_A + p * NPTS;   /* column-side potential (reference A) */
  float* Bp = ws + OFF_B + p * NPTS;   /* row-side potential   (reference B) */
  float* err = ws + OFF_ERR;
  unsigned* ubase = reinterpret_cast<unsigned*>(ws);
  unsigned* barc = ubase + OFF_BARC + g;
  unsigned* done = ubase + OFF_DONE;

  unsigned phase = 0;
  for (int it = 0; it < NITS; ++it) {
    if (it > 0) {
      /* group-wide activity, mirroring the reference while-loop cond */
      float ae = 0.f, be = 0.f;
#pragma unroll
      for (int q = 0; q < 4; ++q) {
        ae = fmaxf(ae, aload(&err[((it-1)*8 + g*4 + q)*2 + 0]));
        be = fmaxf(be, aload(&err[((it-1)*8 + g*4 + q)*2 + 1]));
      }
      const float sc = EPSC / (float)NPTS;
      if (!((sc*ae >= TOLC) || (sc*be >= TOLC))) break;
    }
    /* A-half: reduce over rows (B-potential), update column potentials */
    half_update(rowSv, Bp, colPts, colNrm, Ap,
                err + ((it*8+p)*2+0), blk, tid, rowv, comb);
    gbar(barc, 128u * ++phase);
    /* B-half: reduce over cols (fresh A), update row potentials */
    half_update(colSv, Ap, rowPts, rowNrm, Bp,
                err + ((it*8+p)*2+1), blk, tid, rowv, comb);
    gbar(barc, 128u * ++phase);
  }

  /* cost = sum_ij exp(A_j + B_i - C/eps) * C_ij  (scale 1/(n*m) at the end) */
  {
    for (int i = tid; i < NPTS; i += 1024) {
      float4 v = rowSv[i];
      float bv = aload(&Bp[i]);
      v.w += L2E * bv;
      rowv[i] = v;
      bst[i] = EPSC * bv;
    }
    __syncthreads();
    const int wave = tid >> 6, lane = tid & 63;
    const int ih = wave >> 3, jq = wave & 7;
    const int j0 = blk * 64 + jq * 8;
    float y0[8], y1[8], y2[8], Q[8], EA[8];
#pragma unroll
    for (int q = 0; q < 8; ++q) {
      int j = j0 + q;
      y0[q] = colPts[j*3+0]; y1[q] = colPts[j*3+1]; y2[q] = colPts[j*3+2];
      float aj = aload(&Ap[j]);
      Q[q] = L2E * (aj - colNrm[j] * INV_EPS);
      EA[q] = EPSC * aj;
    }
    float acc = 0.f;
    const float4* basep = rowv + ih * 1024;
#pragma unroll 2
    for (int stp = 0; stp < 16; ++stp) {
      int il = stp * 64 + lane;
      float4 v = basep[il];
      float eb = bst[ih * 1024 + il];
#pragma unroll
      for (int q = 0; q < 8; ++q) {
        float m = v.w + Q[q];
        m = fmaf(v.x, y0[q], m);
        m = fmaf(v.y, y1[q], m);
        m = fmaf(v.z, y2[q], m);
        float e = __builtin_amdgcn_exp2f(m);           /* transp * (n*m) */
        float Cv = fmaf(-(EPSC*LN2C), m, eb + EA[q]);  /* C = eps*(A+B - m*ln2) */
        acc = fmaf(e, Cv, acc);
      }
    }
    acc = wsum(acc);
    if (lane == 0) atomicAdd(ws + OFF_COST + p, acc);
  }

  /* last block to finish assembles the 5 outputs */
  if (tid == 0) {
    __threadfence();
    unsigned old = __hip_atomic_fetch_add(done, 1u, __ATOMIC_RELAXED, __HIP_MEMORY_SCOPE_AGENT);
    if (old == 255u) {
      __threadfence();
#pragma unroll
      for (int k = 0; k < 4; ++k)
        out[k] = (aload(ws + OFF_COST + k) - 0.5f * aload(ws + OFF_COST + 4 + k)) *
                 (1.0f / ((float)NPTS * (float)NPTS));
      out[4] = aload(ws + OFF_CHAM);
    }
  }
}

extern "C" void kernel_launch(void* const* d_in, const int* in_sizes, int n_in,
                              void* d_out, int out_size, void* d_ws, size_t ws_size,
                              hipStream_t stream) {
  const float* preds = (const float*)d_in[0];
  const float* gts   = (const float*)d_in[1];
  float* wsf  = (float*)d_ws;
  float* outf = (float*)d_out;

  hipMemsetAsync(d_ws, 0, ZERO_FLOATS * sizeof(float), stream);
  prep_k<<<64, 256, 0, stream>>>(preds, gts, wsf);
  chamfer_k<<<64, 256, 0, stream>>>(preds, gts, wsf);

  void* args[] = { (void*)&preds, (void*)&gts, (void*)&wsf, (void*)&outf };
  hipLaunchCooperativeKernel((void*)sink_k, dim3(256), dim3(1024), args, 0, stream);
}

// Round 7
// 2119.230 us; speedup vs baseline: 1.6001x; 1.0946x over previous
//
#include <hip/hip_runtime.h>

#define NPTS 2048
#define NB 4
#define NITS 50
#define TOLC 1e-3f
#define EPSC 0.1f
#define INV_EPS 10.0f
#define LAC (-1.3862943611198906f)  /* log(1/4) */
#define L2E 1.4426950408889634f
#define LN2C 0.6931471805599453f
#define KS (L2E*2.0f*INV_EPS)
#define NSUB 16
#define CSTRIDE 16   /* uints; 64B between sub-counters */

/* workspace layout (float offsets). First ZERO_FLOATS are zero-initialized. */
#define OFF_A 0            /* [8][2048] column-side potentials */
#define OFF_B 16384        /* [8][2048] row-side potentials    */
#define OFF_ERR 32768      /* [50][8][2] |delta| sums          */
#define OFF_COST 33568     /* [8] raw transp*C sums            */
#define OFF_CHAM 33576     /* [1] chamfer                      */
#define OFF_BARC 33600     /* [2][16] stride-16 uint arrival sub-counters */
#define OFF_DONE 34112     /* [16] stride-16 uint done sub-counters */
#define ZERO_FLOATS 34368
#define OFF_SVP 34384      /* [4][2048] float4 scaled preds (w = -L2E*rn*INV_EPS) */
#define OFF_SVG 67152      /* [4][2048] float4 scaled gts   */

__device__ __forceinline__ float wsum(float v) {
#pragma unroll
  for (int o = 32; o; o >>= 1) v += __shfl_xor(v, o, 64);
  return v;
}

/* agent-scope (device) atomic load/store: coherent past the per-XCD L2s. */
__device__ __forceinline__ float aload(const float* p) {
  return __hip_atomic_load(p, __ATOMIC_RELAXED, __HIP_MEMORY_SCOPE_AGENT);
}
__device__ __forceinline__ void astore(float* p, float v) {
  __hip_atomic_store(p, v, __ATOMIC_RELAXED, __HIP_MEMORY_SCOPE_AGENT);
}

/* group barrier, contention-split: 16 sub-counters 64B apart, 8 RMWs each
   (round 6 measured 17.5us with 128 RMWs on ONE address). Wave 0 lanes 0-15
   poll all sub-counters in parallel; shfl-sum; monotonic targets, no reset. */
__device__ __forceinline__ void gbar(unsigned* c, int blk, unsigned target) {
  __syncthreads();
  if (threadIdx.x < 64) {
    if (threadIdx.x == 0) {
      __threadfence();   /* release my block's global writes */
      __hip_atomic_fetch_add(c + (blk & (NSUB-1)) * CSTRIDE, 1u,
                             __ATOMIC_RELAXED, __HIP_MEMORY_SCOPE_AGENT);
    }
    int total;
    do {
      unsigned v = 0u;
      if (threadIdx.x < NSUB)
        v = __hip_atomic_load(c + threadIdx.x * CSTRIDE,
                              __ATOMIC_RELAXED, __HIP_MEMORY_SCOPE_AGENT);
      total = (int)v;
#pragma unroll
      for (int o = 32; o; o >>= 1) total += __shfl_xor(total, o, 64);
      if ((unsigned)total < target) __builtin_amdgcn_s_sleep(1);
    } while ((unsigned)total < target);
    if (threadIdx.x == 0) __threadfence();  /* acquire remote writes */
  }
  __syncthreads();
}

__global__ void prep_k(const float* __restrict__ preds, const float* __restrict__ gts,
                       float* __restrict__ ws) {
  int idx = blockIdx.x * 256 + threadIdx.x;
  if (idx >= 2 * NB * NPTS) return;
  int side = idx >> 13;                 /* 0: preds, 1: gts */
  int k = idx & (NB * NPTS - 1);
  const float* src = side ? gts : preds;
  float x = src[k*3+0], y = src[k*3+1], z = src[k*3+2];
  float rn = x*x + y*y + z*z;
  float4* sv = reinterpret_cast<float4*>(ws + (side ? OFF_SVG : OFF_SVP));
  sv[k] = make_float4(KS*x, KS*y, KS*z, -L2E*rn*INV_EPS);
}

/* dir 0: rows=gts cols=preds (loss_2); dir 1: rows=preds cols=gts (loss_1). */
__global__ __launch_bounds__(256) void chamfer_k(const float* __restrict__ preds,
                                                 const float* __restrict__ gts,
                                                 float* __restrict__ ws) {
  __shared__ float4 colv[NPTS];
  int dir = blockIdx.x >> 5;
  int b = (blockIdx.x >> 3) & 3;
  int chunk = blockIdx.x & 7;
  const float* rowP = dir ? preds : gts;
  const float* colP = dir ? gts : preds;
  for (int c = threadIdx.x; c < NPTS; c += 256) {
    const float* p = colP + (b * NPTS + c) * 3;
    colv[c] = make_float4(p[0], p[1], p[2], p[0]*p[0] + p[1]*p[1] + p[2]*p[2]);
  }
  __syncthreads();
  int r = chunk * 256 + threadIdx.x;
  const float* p = rowP + (b * NPTS + r) * 3;
  float rn = p[0]*p[0] + p[1]*p[1] + p[2]*p[2];
  float nx = -2.f*p[0], ny = -2.f*p[1], nz = -2.f*p[2];
  float mn = 1e30f;
  for (int c = 0; c < NPTS; ++c) {
    float4 v = colv[c];
    float t = fmaf(nx, v.x, fmaf(ny, v.y, fmaf(nz, v.z, v.w)));
    mn = fminf(mn, t);
  }
  mn += rn;
  mn = wsum(mn);
  if ((threadIdx.x & 63) == 0) atomicAdd(ws + OFF_CHAM, mn * (1.0f/8192.0f));
}

/* One Sinkhorn half-update for one problem, one block's 64 output slots.
   Reduction panel staged in two 1024-row passes (16KB LDS instead of 32KB).
   oSv.w encodes -L2E*rn/eps, so c = LAC + oSv.w*ln2 (norm arrays dropped). */
__device__ __forceinline__ void half_update(const float4* __restrict__ sv,
    const float* __restrict__ sPot, const float* __restrict__ oPts,
    const float4* __restrict__ oSv, float* __restrict__ oPot,
    float* __restrict__ errSlot, int blk, int tid,
    float4* rowv, float (*comb)[64]) {
  const int wave = tid >> 6, lane = tid & 63;
  const int ih = wave >> 3, jq = wave & 7;
  const int o0 = blk * 64 + jq * 8;
  float y0[8], y1[8], y2[8], S[8], s[8];
#pragma unroll
  for (int q = 0; q < 8; ++q) {
    int o = o0 + q;
    y0[q] = oPts[o*3+0]; y1[q] = oPts[o*3+1]; y2[q] = oPts[o*3+2];
    float c = LAC + oSv[o].w * LN2C;
    S[q] = L2E * (-aload(&oPot[o]) - c);   /* base-2 shift from previous potential */
    s[q] = 0.f;
  }
#pragma unroll
  for (int h = 0; h < 2; ++h) {
    {
      float4 v = sv[h * 1024 + tid];
      v.w += L2E * aload(&sPot[h * 1024 + tid]);
      rowv[tid] = v;
    }
    __syncthreads();
    const float4* basep = rowv + ih * 512;
#pragma unroll 2
    for (int stp = 0; stp < 8; ++stp) {
      float4 v = basep[stp * 64 + lane];
#pragma unroll
      for (int q = 0; q < 8; ++q) {
        float m = v.w - S[q];
        m = fmaf(v.x, y0[q], m);
        m = fmaf(v.y, y1[q], m);
        m = fmaf(v.z, y2[q], m);
        s[q] += __builtin_amdgcn_exp2f(m);
      }
    }
    __syncthreads();
  }
#pragma unroll
  for (int q = 0; q < 8; ++q) s[q] = wsum(s[q]);
  if (lane == 0) {
#pragma unroll
    for (int q = 0; q < 8; ++q) comb[ih][jq * 8 + q] = s[q];
  }
  __syncthreads();
  if (tid < 64) {
    int o = blk * 64 + tid;
    float stot = fmaxf(comb[0][tid] + comb[1][tid], 1e-38f);
    float c = LAC + oSv[o].w * LN2C;
    float Sv = L2E * (-aload(&oPot[o]) - c);
    float nv = -c - LN2C * (__builtin_amdgcn_logf(stot) + Sv);
    float d = fabsf(nv - aload(&oPot[o]));
    astore(&oPot[o], nv);
    d = wsum(d);
    if (tid == 0) atomicAdd(errSlot, d);
  }
  __syncthreads();
}

__global__ __launch_bounds__(1024, 4) void sink_k(const float* __restrict__ preds,
    const float* __restrict__ gts, float* __restrict__ ws, float* __restrict__ out) {
  __shared__ float4 rowv[1024];   /* 16KB staging (one half-panel) */
  __shared__ float bstv[1024];    /* 4KB: eps*B for the cost pass  */
  __shared__ float comb[2][64];
  const int p = blockIdx.x & 7;        /* 0-3 = C(gts,preds) group 0, 4-7 = C(preds,preds) group 1 */
  const int blk = blockIdx.x >> 3;     /* 0..31 */
  const int b = p & 3;
  const int g = p >> 2;
  const bool fs = (g == 0);
  const int tid = threadIdx.x;

  const float* colPts = preds + b * NPTS * 3;
  const float4* colSv = reinterpret_cast<const float4*>(ws + OFF_SVP) + b * NPTS;
  const float* rowPts = fs ? gts + b * NPTS * 3 : colPts;
  const float4* rowSv = fs ? reinterpret_cast<const float4*>(ws + OFF_SVG) + b * NPTS : colSv;
  float* Ap = ws + OFF_A + p * NPTS;   /* column-side potential (reference A) */
  float* Bp = ws + OFF_B + p * NPTS;   /* row-side potential   (reference B) */
  float* err = ws + OFF_ERR;
  unsigned* ubase = reinterpret_cast<unsigned*>(ws);
  unsigned* barc = ubase + OFF_BARC + g * (NSUB * CSTRIDE);
  unsigned* dsub = ubase + OFF_DONE;

  unsigned phase = 0;
  for (int it = 0; it < NITS; ++it) {
    if (it > 0) {
      /* group-wide activity, mirroring the reference while-loop cond */
      float ae = 0.f, be = 0.f;
#pragma unroll
      for (int q = 0; q < 4; ++q) {
        ae = fmaxf(ae, aload(&err[((it-1)*8 + g*4 + q)*2 + 0]));
        be = fmaxf(be, aload(&err[((it-1)*8 + g*4 + q)*2 + 1]));
      }
      const float sc = EPSC / (float)NPTS;
      if (!((sc*ae >= TOLC) || (sc*be >= TOLC))) break;
    }
    /* A-half: reduce over rows (B-potential), update column potentials */
    half_update(rowSv, Bp, colPts, colSv, Ap,
                err + ((it*8+p)*2+0), blk, tid, rowv, comb);
    gbar(barc, blk, 128u * ++phase);
    /* B-half: reduce over cols (fresh A), update row potentials */
    half_update(colSv, Ap, rowPts, rowSv, Bp,
                err + ((it*8+p)*2+1), blk, tid, rowv, comb);
    gbar(barc, blk, 128u * ++phase);
  }

  /* cost = sum_ij exp(A_j + B_i - C/eps) * C_ij  (scale 1/(n*m) at the end) */
  {
    const int wave = tid >> 6, lane = tid & 63;
    const int ih = wave >> 3, jq = wave & 7;
    const int j0 = blk * 64 + jq * 8;
    float y0[8], y1[8], y2[8], Q[8], EA[8];
#pragma unroll
    for (int q = 0; q < 8; ++q) {
      int j = j0 + q;
      y0[q] = colPts[j*3+0]; y1[q] = colPts[j*3+1]; y2[q] = colPts[j*3+2];
      float aj = aload(&Ap[j]);
      Q[q] = L2E * aj + colSv[j].w;   /* = L2E*(aj - rn_j/eps) */
      EA[q] = EPSC * aj;
    }
    float acc = 0.f;
#pragma unroll
    for (int h = 0; h < 2; ++h) {
      {
        float4 v = rowSv[h * 1024 + tid];
        float bv = aload(&Bp[h * 1024 + tid]);
        v.w += L2E * bv;
        rowv[tid] = v;
        bstv[tid] = EPSC * bv;
      }
      __syncthreads();
      const float4* basep = rowv + ih * 512;
      const float* bb = bstv + ih * 512;
#pragma unroll 2
      for (int stp = 0; stp < 8; ++stp) {
        int il = stp * 64 + lane;
        float4 v = basep[il];
        float eb = bb[il];
#pragma unroll
        for (int q = 0; q < 8; ++q) {
          float m = v.w + Q[q];
          m = fmaf(v.x, y0[q], m);
          m = fmaf(v.y, y1[q], m);
          m = fmaf(v.z, y2[q], m);
          float e = __builtin_amdgcn_exp2f(m);           /* transp * (n*m) */
          float Cv = fmaf(-(EPSC*LN2C), m, eb + EA[q]);  /* C = eps*(A+B - m*ln2) */
          acc = fmaf(e, Cv, acc);
        }
      }
      __syncthreads();
    }
    acc = wsum(acc);
    if (lane == 0) atomicAdd(ws + OFF_COST + p, acc);
  }

  /* done: split arrival counters; only block 0 spins, then writes outputs */
  if (tid == 0) {
    __threadfence();
    __hip_atomic_fetch_add(dsub + (blockIdx.x & (NSUB-1)) * CSTRIDE, 1u,
                           __ATOMIC_RELAXED, __HIP_MEMORY_SCOPE_AGENT);
  }
  if (blockIdx.x == 0 && tid < 64) {
    int total;
    do {
      unsigned v = 0u;
      if (tid < NSUB)
        v = __hip_atomic_load(dsub + tid * CSTRIDE,
                              __ATOMIC_RELAXED, __HIP_MEMORY_SCOPE_AGENT);
      total = (int)v;
#pragma unroll
      for (int o = 32; o; o >>= 1) total += __shfl_xor(total, o, 64);
      if (total < 256) __builtin_amdgcn_s_sleep(1);
    } while (total < 256);
    __threadfence();
    if (tid < 4)
      out[tid] = (aload(ws + OFF_COST + tid) - 0.5f * aload(ws + OFF_COST + 4 + tid)) *
                 (1.0f / ((float)NPTS * (float)NPTS));
    if (tid == 4) out[4] = aload(ws + OFF_CHAM);
  }
}

extern "C" void kernel_launch(void* const* d_in, const int* in_sizes, int n_in,
                              void* d_out, int out_size, void* d_ws, size_t ws_size,
                              hipStream_t stream) {
  const float* preds = (const float*)d_in[0];
  const float* gts   = (const float*)d_in[1];
  float* wsf  = (float*)d_ws;
  float* outf = (float*)d_out;

  hipMemsetAsync(d_ws, 0, ZERO_FLOATS * sizeof(float), stream);
  prep_k<<<64, 256, 0, stream>>>(preds, gts, wsf);
  chamfer_k<<<64, 256, 0, stream>>>(preds, gts, wsf);

  void* args[] = { (void*)&preds, (void*)&gts, (void*)&wsf, (void*)&outf };
  hipLaunchCooperativeKernel((void*)sink_k, dim3(256), dim3(1024), args, 0, stream);
}

// Round 8
// 1460.747 us; speedup vs baseline: 2.3214x; 1.4508x over previous
//
#include <hip/hip_runtime.h>

#define NPTS 2048
#define NB 4
#define NITS 50
#define TOLC 1e-3f
#define EPSC 0.1f
#define INV_EPS 10.0f
#define LAC (-1.3862943611198906f)  /* log(1/4) */
#define L2E 1.4426950408889634f
#define LN2C 0.6931471805599453f
#define KS (L2E*2.0f*INV_EPS)
#define NSUB 16
#define CSTRIDE 16   /* uints; 64B between sub-counters */

/* workspace layout (float offsets). First ZERO_FLOATS are zero-initialized. */
#define OFF_A 0            /* [8][2048] column-side potentials */
#define OFF_B 16384        /* [8][2048] row-side potentials    */
#define OFF_ERR 32768      /* [50][8][2] |delta| sums          */
#define OFF_COST 33568     /* [8] raw transp*C sums            */
#define OFF_CHAM 33576     /* [1] chamfer                      */
#define OFF_BARC 33600     /* [2][16] stride-16 uint arrival sub-counters */
#define OFF_DONE 34112     /* [16] stride-16 uint done sub-counters */
#define ZERO_FLOATS 34368
#define OFF_SVP 34384      /* [4][2048] float4 scaled preds (w = -L2E*rn*INV_EPS) */
#define OFF_SVG 67152      /* [4][2048] float4 scaled gts   */

__device__ __forceinline__ float wsum(float v) {
#pragma unroll
  for (int o = 32; o; o >>= 1) v += __shfl_xor(v, o, 64);
  return v;
}

/* agent-scope (device) atomic load/store: coherent past the per-XCD L2s.
   ALL cross-block data goes through these (or atomicAdd, which is
   device-scope), so no cache-maintenance fences are needed anywhere. */
__device__ __forceinline__ float aload(const float* p) {
  return __hip_atomic_load(p, __ATOMIC_RELAXED, __HIP_MEMORY_SCOPE_AGENT);
}
__device__ __forceinline__ void astore(float* p, float v) {
  __hip_atomic_store(p, v, __ATOMIC_RELAXED, __HIP_MEMORY_SCOPE_AGENT);
}

/* FENCE-FREE group barrier (the round-8 experiment).
   Round 6: single counter = 17.5us/barrier. Round 7: 16-way split = 16us
   -> contention is NOT the term. Hypothesis: __threadfence's buffer_wbl2 /
   buffer_inv (XCD-L2-wide writeback/invalidate, 2 per block per phase) is.
   Remove fences entirely: visibility holds because (a) __syncthreads drains
   each wave's outstanding stores (s_waitcnt vmcnt(0) before s_barrier --
   rounds 6/7 correctness already depended on this), and (b) every
   cross-block datum is an agent-scope op serialized at the LLC. */
__device__ __forceinline__ void gbar(unsigned* c, int blk, unsigned target) {
  __syncthreads();   /* drains all waves' astores/atomicAdds (vmcnt(0)) */
  if (threadIdx.x < 64) {
    if (threadIdx.x == 0) {
      __builtin_amdgcn_s_waitcnt(0);
      __hip_atomic_fetch_add(c + (blk & (NSUB-1)) * CSTRIDE, 1u,
                             __ATOMIC_RELAXED, __HIP_MEMORY_SCOPE_AGENT);
    }
    int total;
    do {
      unsigned v = 0u;
      if (threadIdx.x < NSUB)
        v = __hip_atomic_load(c + threadIdx.x * CSTRIDE,
                              __ATOMIC_RELAXED, __HIP_MEMORY_SCOPE_AGENT);
      total = (int)v;
#pragma unroll
      for (int o = 32; o; o >>= 1) total += __shfl_xor(total, o, 64);
      if ((unsigned)total < target) __builtin_amdgcn_s_sleep(1);
    } while ((unsigned)total < target);
  }
  __syncthreads();
}

__global__ void prep_k(const float* __restrict__ preds, const float* __restrict__ gts,
                       float* __restrict__ ws) {
  int idx = blockIdx.x * 256 + threadIdx.x;
  if (idx >= 2 * NB * NPTS) return;
  int side = idx >> 13;                 /* 0: preds, 1: gts */
  int k = idx & (NB * NPTS - 1);
  const float* src = side ? gts : preds;
  float x = src[k*3+0], y = src[k*3+1], z = src[k*3+2];
  float rn = x*x + y*y + z*z;
  float4* sv = reinterpret_cast<float4*>(ws + (side ? OFF_SVG : OFF_SVP));
  sv[k] = make_float4(KS*x, KS*y, KS*z, -L2E*rn*INV_EPS);
}

/* dir 0: rows=gts cols=preds (loss_2); dir 1: rows=preds cols=gts (loss_1). */
__global__ __launch_bounds__(256) void chamfer_k(const float* __restrict__ preds,
                                                 const float* __restrict__ gts,
                                                 float* __restrict__ ws) {
  __shared__ float4 colv[NPTS];
  int dir = blockIdx.x >> 5;
  int b = (blockIdx.x >> 3) & 3;
  int chunk = blockIdx.x & 7;
  const float* rowP = dir ? preds : gts;
  const float* colP = dir ? gts : preds;
  for (int c = threadIdx.x; c < NPTS; c += 256) {
    const float* p = colP + (b * NPTS + c) * 3;
    colv[c] = make_float4(p[0], p[1], p[2], p[0]*p[0] + p[1]*p[1] + p[2]*p[2]);
  }
  __syncthreads();
  int r = chunk * 256 + threadIdx.x;
  const float* p = rowP + (b * NPTS + r) * 3;
  float rn = p[0]*p[0] + p[1]*p[1] + p[2]*p[2];
  float nx = -2.f*p[0], ny = -2.f*p[1], nz = -2.f*p[2];
  float mn = 1e30f;
  for (int c = 0; c < NPTS; ++c) {
    float4 v = colv[c];
    float t = fmaf(nx, v.x, fmaf(ny, v.y, fmaf(nz, v.z, v.w)));
    mn = fminf(mn, t);
  }
  mn += rn;
  mn = wsum(mn);
  if ((threadIdx.x & 63) == 0) atomicAdd(ws + OFF_CHAM, mn * (1.0f/8192.0f));
}

/* One Sinkhorn half-update for one problem, one block's 64 output slots.
   Reduction panel staged in two 1024-row passes (16KB LDS).
   oSv.w encodes -L2E*rn/eps, so c = LAC + oSv.w*ln2. */
__device__ __forceinline__ void half_update(const float4* __restrict__ sv,
    const float* __restrict__ sPot, const float* __restrict__ oPts,
    const float4* __restrict__ oSv, float* __restrict__ oPot,
    float* __restrict__ errSlot, int blk, int tid,
    float4* rowv, float (*comb)[64]) {
  const int wave = tid >> 6, lane = tid & 63;
  const int ih = wave >> 3, jq = wave & 7;
  const int o0 = blk * 64 + jq * 8;
  float y0[8], y1[8], y2[8], S[8], s[8];
#pragma unroll
  for (int q = 0; q < 8; ++q) {
    int o = o0 + q;
    y0[q] = oPts[o*3+0]; y1[q] = oPts[o*3+1]; y2[q] = oPts[o*3+2];
    float c = LAC + oSv[o].w * LN2C;
    S[q] = L2E * (-aload(&oPot[o]) - c);   /* base-2 shift from previous potential */
    s[q] = 0.f;
  }
#pragma unroll
  for (int h = 0; h < 2; ++h) {
    {
      float4 v = sv[h * 1024 + tid];
      v.w += L2E * aload(&sPot[h * 1024 + tid]);
      rowv[tid] = v;
    }
    __syncthreads();
    const float4* basep = rowv + ih * 512;
#pragma unroll 2
    for (int stp = 0; stp < 8; ++stp) {
      float4 v = basep[stp * 64 + lane];
#pragma unroll
      for (int q = 0; q < 8; ++q) {
        float m = v.w - S[q];
        m = fmaf(v.x, y0[q], m);
        m = fmaf(v.y, y1[q], m);
        m = fmaf(v.z, y2[q], m);
        s[q] += __builtin_amdgcn_exp2f(m);
      }
    }
    __syncthreads();
  }
#pragma unroll
  for (int q = 0; q < 8; ++q) s[q] = wsum(s[q]);
  if (lane == 0) {
#pragma unroll
    for (int q = 0; q < 8; ++q) comb[ih][jq * 8 + q] = s[q];
  }
  __syncthreads();
  if (tid < 64) {
    int o = blk * 64 + tid;
    float stot = fmaxf(comb[0][tid] + comb[1][tid], 1e-38f);
    float c = LAC + oSv[o].w * LN2C;
    float Sv = L2E * (-aload(&oPot[o]) - c);
    float nv = -c - LN2C * (__builtin_amdgcn_logf(stot) + Sv);
    float d = fabsf(nv - aload(&oPot[o]));
    astore(&oPot[o], nv);
    d = wsum(d);
    if (tid == 0) atomicAdd(errSlot, d);
  }
  __syncthreads();
}

__global__ __launch_bounds__(1024, 4) void sink_k(const float* __restrict__ preds,
    const float* __restrict__ gts, float* __restrict__ ws, float* __restrict__ out) {
  __shared__ float4 rowv[1024];   /* 16KB staging (one half-panel) */
  __shared__ float bstv[1024];    /* 4KB: eps*B for the cost pass  */
  __shared__ float comb[2][64];
  const int p = blockIdx.x & 7;        /* 0-3 = C(gts,preds) group 0, 4-7 = C(preds,preds) group 1 */
  const int blk = blockIdx.x >> 3;     /* 0..31 */
  const int b = p & 3;
  const int g = p >> 2;
  const bool fs = (g == 0);
  const int tid = threadIdx.x;

  const float* colPts = preds + b * NPTS * 3;
  const float4* colSv = reinterpret_cast<const float4*>(ws + OFF_SVP) + b * NPTS;
  const float* rowPts = fs ? gts + b * NPTS * 3 : colPts;
  const float4* rowSv = fs ? reinterpret_cast<const float4*>(ws + OFF_SVG) + b * NPTS : colSv;
  float* Ap = ws + OFF_A + p * NPTS;   /* column-side potential (reference A) */
  float* Bp = ws + OFF_B + p * NPTS;   /* row-side potential   (reference B) */
  float* err = ws + OFF_ERR;
  unsigned* ubase = reinterpret_cast<unsigned*>(ws);
  unsigned* barc = ubase + OFF_BARC + g * (NSUB * CSTRIDE);
  unsigned* dsub = ubase + OFF_DONE;

  unsigned phase = 0;
  for (int it = 0; it < NITS; ++it) {
    if (it > 0) {
      /* group-wide activity, mirroring the reference while-loop cond.
         err slots were complete at the LLC before the barrier counters
         advanced, so relaxed loads here see final values. */
      float ae = 0.f, be = 0.f;
#pragma unroll
      for (int q = 0; q < 4; ++q) {
        ae = fmaxf(ae, aload(&err[((it-1)*8 + g*4 + q)*2 + 0]));
        be = fmaxf(be, aload(&err[((it-1)*8 + g*4 + q)*2 + 1]));
      }
      const float sc = EPSC / (float)NPTS;
      if (!((sc*ae >= TOLC) || (sc*be >= TOLC))) break;
    }
    /* A-half: reduce over rows (B-potential), update column potentials */
    half_update(rowSv, Bp, colPts, colSv, Ap,
                err + ((it*8+p)*2+0), blk, tid, rowv, comb);
    gbar(barc, blk, 128u * ++phase);
    /* B-half: reduce over cols (fresh A), update row potentials */
    half_update(colSv, Ap, rowPts, rowSv, Bp,
                err + ((it*8+p)*2+1), blk, tid, rowv, comb);
    gbar(barc, blk, 128u * ++phase);
  }

  /* cost = sum_ij exp(A_j + B_i - C/eps) * C_ij  (scale 1/(n*m) at the end) */
  {
    const int wave = tid >> 6, lane = tid & 63;
    const int ih = wave >> 3, jq = wave & 7;
    const int j0 = blk * 64 + jq * 8;
    float y0[8], y1[8], y2[8], Q[8], EA[8];
#pragma unroll
    for (int q = 0; q < 8; ++q) {
      int j = j0 + q;
      y0[q] = colPts[j*3+0]; y1[q] = colPts[j*3+1]; y2[q] = colPts[j*3+2];
      float aj = aload(&Ap[j]);
      Q[q] = L2E * aj + colSv[j].w;   /* = L2E*(aj - rn_j/eps) */
      EA[q] = EPSC * aj;
    }
    float acc = 0.f;
#pragma unroll
    for (int h = 0; h < 2; ++h) {
      {
        float4 v = rowSv[h * 1024 + tid];
        float bv = aload(&Bp[h * 1024 + tid]);
        v.w += L2E * bv;
        rowv[tid] = v;
        bstv[tid] = EPSC * bv;
      }
      __syncthreads();
      const float4* basep = rowv + ih * 512;
      const float* bb = bstv + ih * 512;
#pragma unroll 2
      for (int stp = 0; stp < 8; ++stp) {
        int il = stp * 64 + lane;
        float4 v = basep[il];
        float eb = bb[il];
#pragma unroll
        for (int q = 0; q < 8; ++q) {
          float m = v.w + Q[q];
          m = fmaf(v.x, y0[q], m);
          m = fmaf(v.y, y1[q], m);
          m = fmaf(v.z, y2[q], m);
          float e = __builtin_amdgcn_exp2f(m);           /* transp * (n*m) */
          float Cv = fmaf(-(EPSC*LN2C), m, eb + EA[q]);  /* C = eps*(A+B - m*ln2) */
          acc = fmaf(e, Cv, acc);
        }
      }
      __syncthreads();
    }
    acc = wsum(acc);
    if (lane == 0) atomicAdd(ws + OFF_COST + p, acc);
  }

  /* done: drain ALL waves' cost-adds (syncthreads), then split arrival
     counters; only block 0 spins, then writes outputs. */
  __syncthreads();
  if (tid == 0) {
    __builtin_amdgcn_s_waitcnt(0);
    __hip_atomic_fetch_add(dsub + (blockIdx.x & (NSUB-1)) * CSTRIDE, 1u,
                           __ATOMIC_RELAXED, __HIP_MEMORY_SCOPE_AGENT);
  }
  if (blockIdx.x == 0 && tid < 64) {
    int total;
    do {
      unsigned v = 0u;
      if (tid < NSUB)
        v = __hip_atomic_load(dsub + tid * CSTRIDE,
                              __ATOMIC_RELAXED, __HIP_MEMORY_SCOPE_AGENT);
      total = (int)v;
#pragma unroll
      for (int o = 32; o; o >>= 1) total += __shfl_xor(total, o, 64);
      if (total < 256) __builtin_amdgcn_s_sleep(1);
    } while (total < 256);
    if (tid < 4)
      out[tid] = (aload(ws + OFF_COST + tid) - 0.5f * aload(ws + OFF_COST + 4 + tid)) *
                 (1.0f / ((float)NPTS * (float)NPTS));
    if (tid == 4) out[4] = aload(ws + OFF_CHAM);
  }
}

extern "C" void kernel_launch(void* const* d_in, const int* in_sizes, int n_in,
                              void* d_out, int out_size, void* d_ws, size_t ws_size,
                              hipStream_t stream) {
  const float* preds = (const float*)d_in[0];
  const float* gts   = (const float*)d_in[1];
  float* wsf  = (float*)d_ws;
  float* outf = (float*)d_out;

  hipMemsetAsync(d_ws, 0, ZERO_FLOATS * sizeof(float), stream);
  prep_k<<<64, 256, 0, stream>>>(preds, gts, wsf);
  chamfer_k<<<64, 256, 0, stream>>>(preds, gts, wsf);

  void* args[] = { (void*)&preds, (void*)&gts, (void*)&wsf, (void*)&outf };
  hipLaunchCooperativeKernel((void*)sink_k, dim3(256), dim3(1024), args, 0, stream);
}

// Round 10
// 1155.704 us; speedup vs baseline: 2.9341x; 1.2639x over previous
//
#include <hip/hip_runtime.h>

#define NPTS 2048
#define NB 4
#define NITS 50
#define TOLC 1e-3f
#define EPSC 0.1f
#define INV_EPS 10.0f
#define LAC (-1.3862943611198906f)  /* log(1/4) */
#define L2E 1.4426950408889634f
#define LN2C 0.6931471805599453f
#define KS (L2E*2.0f*INV_EPS)
#define CSTRIDE 16   /* uints; 64B between per-problem counters */

/* workspace layout (float offsets). First ZERO_FLOATS are zero-initialized.
   Potentials are PARITY-BUFFERED: iteration it writes buffer (it&1), reads
   (1-(it&1)); enables 1-deep speculative iterations with exact rollback. */
#define OFF_A 0            /* [2][8][2048] column-side potentials */
#define OFF_B 32768        /* [2][8][2048] row-side potentials    */
#define OFF_ERR 65536      /* [50][8][2] |delta| sums             */
#define OFF_COST 66336     /* [8] raw transp*C sums               */
#define OFF_CHAM 66344     /* [1] chamfer                         */
#define OFF_BARC 66352     /* [8] stride-16 uint per-problem arrival counters */
#define OFF_DONE 66480     /* [1] uint done counter               */
#define ZERO_FLOATS 66496

__device__ __forceinline__ float wsum(float v) {
#pragma unroll
  for (int o = 32; o; o >>= 1) v += __shfl_xor(v, o, 64);
  return v;
}

/* agent-scope (device) atomic load/store: coherent past the per-XCD L2s. */
__device__ __forceinline__ float aload(const float* p) {
  return __hip_atomic_load(p, __ATOMIC_RELAXED, __HIP_MEMORY_SCOPE_AGENT);
}
__device__ __forceinline__ void astore(float* p, float v) {
  __hip_atomic_store(p, v, __ATOMIC_RELAXED, __HIP_MEMORY_SCOPE_AGENT);
}

/* per-problem (32-block) fence-free barrier; monotonic counter, tid-0 spins.
   Wave 0 issued ALL of this phase's global writes (potentials tid<64, err
   tid 0); __syncthreads drains every wave's stores (s_waitcnt vmcnt(0)
   before s_barrier), so the arrival add orders after them at the LLC. */
__device__ __forceinline__ void pbar(unsigned* c, unsigned target) {
  __syncthreads();
  if (threadIdx.x == 0) {
    __builtin_amdgcn_s_waitcnt(0);
    __hip_atomic_fetch_add(c, 1u, __ATOMIC_RELAXED, __HIP_MEMORY_SCOPE_AGENT);
    while (__hip_atomic_load(c, __ATOMIC_RELAXED, __HIP_MEMORY_SCOPE_AGENT) < target)
      __builtin_amdgcn_s_sleep(1);
  }
  __syncthreads();
}

/* dir 0: rows=gts cols=preds (loss_2); dir 1: rows=preds cols=gts (loss_1). */
__global__ __launch_bounds__(256) void chamfer_k(const float* __restrict__ preds,
                                                 const float* __restrict__ gts,
                                                 float* __restrict__ ws) {
  __shared__ float4 colv[NPTS];
  int dir = blockIdx.x >> 5;
  int b = (blockIdx.x >> 3) & 3;
  int chunk = blockIdx.x & 7;
  const float* rowP = dir ? preds : gts;
  const float* colP = dir ? gts : preds;
  for (int c = threadIdx.x; c < NPTS; c += 256) {
    const float* p = colP + (b * NPTS + c) * 3;
    colv[c] = make_float4(p[0], p[1], p[2], p[0]*p[0] + p[1]*p[1] + p[2]*p[2]);
  }
  __syncthreads();
  int r = chunk * 256 + threadIdx.x;
  const float* p = rowP + (b * NPTS + r) * 3;
  float rn = p[0]*p[0] + p[1]*p[1] + p[2]*p[2];
  float nx = -2.f*p[0], ny = -2.f*p[1], nz = -2.f*p[2];
  float mn = 1e30f;
  for (int c = 0; c < NPTS; ++c) {
    float4 v = colv[c];
    float t = fmaf(nx, v.x, fmaf(ny, v.y, fmaf(nz, v.z, v.w)));
    mn = fminf(mn, t);
  }
  mn += rn;
  mn = wsum(mn);
  if ((threadIdx.x & 63) == 0) atomicAdd(ws + OFF_CHAM, mn * (1.0f/8192.0f));
}

/* One Sinkhorn half-update. Reduce-side scaled panel svL lives in LDS
   (staged once at kernel start); only the 8KB potential vector is staged
   per phase. oCw[o].w = -L2E*rn_o/eps encodes the output-side norm. */
__device__ __forceinline__ void half_update(const float4* __restrict__ svL,
    const float* __restrict__ potSrc, const float* __restrict__ oPts,
    const float4* __restrict__ oCw, const float* __restrict__ oPrev,
    float* __restrict__ oNew, float* __restrict__ errSlot,
    int blk, int tid, float* __restrict__ pot, float (*comb)[64]) {
  pot[tid]        = aload(potSrc + tid);
  pot[tid + 1024] = aload(potSrc + tid + 1024);
  __syncthreads();
  const int wave = tid >> 6, lane = tid & 63;
  const int ih = wave >> 3, jq = wave & 7;
  const int o0 = blk * 64 + jq * 8;
  float y0[8], y1[8], y2[8], S[8], s[8];
#pragma unroll
  for (int q = 0; q < 8; ++q) {
    int o = o0 + q;
    y0[q] = oPts[o*3+0]; y1[q] = oPts[o*3+1]; y2[q] = oPts[o*3+2];
    float c = LAC + oCw[o].w * LN2C;
    S[q] = L2E * (-aload(&oPrev[o]) - c);  /* base-2 shift from previous potential */
    s[q] = 0.f;
  }
  const float4* basep = svL + ih * 1024;
  const float* potp = pot + ih * 1024;
#pragma unroll 2
  for (int stp = 0; stp < 16; ++stp) {
    int il = stp * 64 + lane;
    float4 v = basep[il];
    float wv = fmaf(L2E, potp[il], v.w);
#pragma unroll
    for (int q = 0; q < 8; ++q) {
      float m = wv - S[q];
      m = fmaf(v.x, y0[q], m);
      m = fmaf(v.y, y1[q], m);
      m = fmaf(v.z, y2[q], m);
      s[q] += __builtin_amdgcn_exp2f(m);
    }
  }
#pragma unroll
  for (int q = 0; q < 8; ++q) s[q] = wsum(s[q]);
  if (lane == 0) {
#pragma unroll
    for (int q = 0; q < 8; ++q) comb[ih][jq * 8 + q] = s[q];
  }
  __syncthreads();
  if (tid < 64) {
    int o = blk * 64 + tid;
    float stot = fmaxf(comb[0][tid] + comb[1][tid], 1e-38f);
    float c = LAC + oCw[o].w * LN2C;
    float pv = aload(&oPrev[o]);
    float Sv = L2E * (-pv - c);
    float nv = -c - LN2C * (__builtin_amdgcn_logf(stot) + Sv);
    float d = fabsf(nv - pv);
    astore(&oNew[o], nv);
    d = wsum(d);
    if (tid == 0) atomicAdd(errSlot, d);
  }
  __syncthreads();
}

__global__ __launch_bounds__(1024, 4) void sink_k(const float* __restrict__ preds,
    const float* __restrict__ gts, float* __restrict__ ws, float* __restrict__ out) {
  __shared__ float4 svR[NPTS];   /* 32KB static reduce-panel (rows) */
  __shared__ float4 svC[NPTS];   /* 32KB static reduce-panel (cols) */
  __shared__ float pot[NPTS];    /* 8KB per-phase potential staging */
  __shared__ float comb[2][64];
  __shared__ int decS;
  const int p = blockIdx.x & 7;        /* 0-3 = C(gts,preds), 4-7 = C(preds,preds) */
  const int blk = blockIdx.x >> 3;     /* 0..31 */
  const int b = p & 3;
  const int g = p >> 2;
  const bool fs = (g == 0);
  const int tid = threadIdx.x;

  const float* colPts = preds + b * NPTS * 3;
  const float* rowPts = fs ? gts + b * NPTS * 3 : colPts;

  /* stage static scaled panels once: sv = (KS*x, KS*y, KS*z, -L2E*rn/eps) */
  for (int i = tid; i < NPTS; i += 1024) {
    const float* q3 = rowPts + i * 3;
    float x = q3[0], y = q3[1], z = q3[2];
    svR[i] = make_float4(KS*x, KS*y, KS*z, -L2E*INV_EPS*(x*x + y*y + z*z));
    const float* c3 = colPts + i * 3;
    float cx = c3[0], cy = c3[1], cz = c3[2];
    svC[i] = make_float4(KS*cx, KS*cy, KS*cz, -L2E*INV_EPS*(cx*cx + cy*cy + cz*cz));
  }

  float* Abase = ws + OFF_A;           /* A[w] at Abase + w*16384 + p*2048 */
  float* Bbase = ws + OFF_B;
  float* err = ws + OFF_ERR;
  unsigned* ub = reinterpret_cast<unsigned*>(ws);
  unsigned* barc = ub + OFF_BARC;
  unsigned* mybar = barc + p * CSTRIDE;
  unsigned* done = ub + OFF_DONE;
  const float sc = EPSC / (float)NPTS;

  int last = NITS - 1;
  /* it == NITS executes the gate only (post-loop boundary check). */
  for (int it = 0; it <= NITS; ++it) {
    const int w = it & 1, r = 1 - (it & 1);
    /* Gate: resolve D(it-1) = reference cond on err[it-2]. Spin only until
       all group problems FINISHED it-2 (counter >= 32*(2it-2)) — one full
       iteration of slack, so this normally doesn't wait. Deterministic:
       reads final (gated) values only -> uniform across all blocks. */
    if (tid == 0) {
      int dec = 1;
      if (it >= 2) {
        unsigned need = 32u * (2u * (unsigned)it - 2u);
        for (;;) {
          unsigned mn = 0xFFFFFFFFu;
#pragma unroll
          for (int q = 0; q < 4; ++q) {
            unsigned v = __hip_atomic_load(barc + (g*4 + q) * CSTRIDE,
                                           __ATOMIC_RELAXED, __HIP_MEMORY_SCOPE_AGENT);
            mn = v < mn ? v : mn;
          }
          if (mn >= need) break;
          __builtin_amdgcn_s_sleep(1);
        }
        int j = it - 2;
        float ae = 0.f, be = 0.f;
#pragma unroll
        for (int q = 0; q < 4; ++q) {
          ae = fmaxf(ae, aload(err + ((j*8 + g*4 + q)*2 + 0)));
          be = fmaxf(be, aload(err + ((j*8 + g*4 + q)*2 + 1)));
        }
        if (!((sc*ae >= TOLC) || (sc*be >= TOLC))) dec = 0;
      }
      decS = dec;
    }
    __syncthreads();
    if (decS == 0) { last = it - 2; break; }   /* it-1 was speculative: rolled back by parity */
    if (it == NITS) { last = NITS - 1; break; }
    /* A-half: reduce over rows (pot = B[r]), outputs = columns, write A[w] */
    half_update(svR, Bbase + r*16384 + p*NPTS, colPts, svC,
                Abase + r*16384 + p*NPTS, Abase + w*16384 + p*NPTS,
                err + ((it*8 + p)*2 + 0), blk, tid, pot, comb);
    pbar(mybar, 32u * (2u*(unsigned)it + 1u));
    /* B-half: reduce over cols (pot = fresh A[w]), outputs = rows, write B[w] */
    half_update(svC, Abase + w*16384 + p*NPTS, rowPts, svR,
                Bbase + r*16384 + p*NPTS, Bbase + w*16384 + p*NPTS,
                err + ((it*8 + p)*2 + 1), blk, tid, pot, comb);
    pbar(mybar, 32u * (2u*(unsigned)it + 2u));
    last = it;
  }

  /* cost = sum_ij exp(A_j + B_i - C/eps) * C_ij, from parity (last&1) */
  {
    const float* Af = Abase + (last & 1)*16384 + p*NPTS;
    const float* Bf = Bbase + (last & 1)*16384 + p*NPTS;
    pot[tid]        = aload(Bf + tid);
    pot[tid + 1024] = aload(Bf + tid + 1024);
    __syncthreads();
    const int wave = tid >> 6, lane = tid & 63;
    const int ih = wave >> 3, jq = wave & 7;
    const int j0 = blk * 64 + jq * 8;
    float y0[8], y1[8], y2[8], Q[8], EA[8];
#pragma unroll
    for (int q = 0; q < 8; ++q) {
      int j = j0 + q;
      y0[q] = colPts[j*3+0]; y1[q] = colPts[j*3+1]; y2[q] = colPts[j*3+2];
      float aj = aload(Af + j);
      Q[q] = L2E * aj + svC[j].w;   /* = L2E*(aj - rn_j/eps) */
      EA[q] = EPSC * aj;
    }
    float acc = 0.f;
    const float4* basep = svR + ih * 1024;
    const float* potp = pot + ih * 1024;
#pragma unroll 2
    for (int stp = 0; stp < 16; ++stp) {
      int il = stp * 64 + lane;
      float4 v = basep[il];
      float pw = potp[il];
      float wv = fmaf(L2E, pw, v.w);
      float eb = EPSC * pw;
#pragma unroll
      for (int q = 0; q < 8; ++q) {
        float m = wv + Q[q];
        m = fmaf(v.x, y0[q], m);
        m = fmaf(v.y, y1[q], m);
        m = fmaf(v.z, y2[q], m);
        float e = __builtin_amdgcn_exp2f(m);           /* transp * (n*m) */
        float Cv = fmaf(-(EPSC*LN2C), m, eb + EA[q]);  /* C = eps*(A+B - m*ln2) */
        acc = fmaf(e, Cv, acc);
      }
    }
    acc = wsum(acc);
    if (lane == 0) atomicAdd(ws + OFF_COST + p, acc);
  }

  /* done: drain cost adds, arrive; block 0 assembles outputs */
  __syncthreads();
  if (tid == 0) {
    __builtin_amdgcn_s_waitcnt(0);
    __hip_atomic_fetch_add(done, 1u, __ATOMIC_RELAXED, __HIP_MEMORY_SCOPE_AGENT);
  }
  if (blockIdx.x == 0) {
    if (tid == 0) {
      while (__hip_atomic_load(done, __ATOMIC_RELAXED, __HIP_MEMORY_SCOPE_AGENT) < 256u)
        __builtin_amdgcn_s_sleep(1);
    }
    __syncthreads();
    if (tid < 4)
      out[tid] = (aload(ws + OFF_COST + tid) - 0.5f * aload(ws + OFF_COST + 4 + tid)) *
                 (1.0f / ((float)NPTS * (float)NPTS));
    if (tid == 4) out[4] = aload(ws + OFF_CHAM);
  }
}

extern "C" void kernel_launch(void* const* d_in, const int* in_sizes, int n_in,
                              void* d_out, int out_size, void* d_ws, size_t ws_size,
                              hipStream_t stream) {
  const float* preds = (const float*)d_in[0];
  const float* gts   = (const float*)d_in[1];
  float* wsf  = (float*)d_ws;
  float* outf = (float*)d_out;

  hipMemsetAsync(d_ws, 0, ZERO_FLOATS * sizeof(float), stream);
  chamfer_k<<<64, 256, 0, stream>>>(preds, gts, wsf);

  void* args[] = { (void*)&preds, (void*)&gts, (void*)&wsf, (void*)&outf };
  hipLaunchCooperativeKernel((void*)sink_k, dim3(256), dim3(1024), args, 0, stream);
}

// Round 11
// 1145.319 us; speedup vs baseline: 2.9607x; 1.0091x over previous
//
#include <hip/hip_runtime.h>

#define NPTS 2048
#define NB 4
#define NITS 50
#define TOLC 1e-3f
#define EPSC 0.1f
#define INV_EPS 10.0f
#define LAC (-1.3862943611198906f)  /* log(1/4) */
#define L2E 1.4426950408889634f
#define LN2C 0.6931471805599453f
#define KS (L2E*2.0f*INV_EPS)
#define CSTRIDE 16   /* uints; 64B between per-block flags */

/* workspace layout (float offsets). First ZERO_FLOATS are zero-initialized.
   Potentials are PARITY-BUFFERED: iteration it writes buffer (it&1), reads
   (1-(it&1)); enables 1-deep speculative iterations with exact rollback. */
#define OFF_A 0            /* [2][8][2048] column-side potentials */
#define OFF_B 32768        /* [2][8][2048] row-side potentials    */
#define OFF_ERR 65536      /* [50][8][2] |delta| sums             */
#define OFF_COST 66336     /* [8] raw transp*C sums               */
#define OFF_CHAM 66344     /* [1] chamfer                         */
#define OFF_FLAG 66352     /* [8][32] stride-16 uint per-block phase flags */
#define OFF_DONE 70448     /* [1] uint done counter               */
#define ZERO_FLOATS 70464

__device__ __forceinline__ float wsum(float v) {
#pragma unroll
  for (int o = 32; o; o >>= 1) v += __shfl_xor(v, o, 64);
  return v;
}

/* agent-scope (device) atomic load/store: coherent past the per-XCD L2s. */
__device__ __forceinline__ float aload(const float* p) {
  return __hip_atomic_load(p, __ATOMIC_RELAXED, __HIP_MEMORY_SCOPE_AGENT);
}
__device__ __forceinline__ void astore(float* p, float v) {
  __hip_atomic_store(p, v, __ATOMIC_RELAXED, __HIP_MEMORY_SCOPE_AGENT);
}
__device__ __forceinline__ unsigned uload(const unsigned* p) {
  return __hip_atomic_load(p, __ATOMIC_RELAXED, __HIP_MEMORY_SCOPE_AGENT);
}

/* FLAG-VECTOR per-problem barrier (round-11 experiment): arrival is ONE
   plain agent-scope store to this block's own 64B-strided flag (no RMW
   chain -- R10 data: 32 serialized atomicAdds ~ 2-3us of the 6.3us phase
   overhead). Detection: wave-0 lanes 0-31 load all 32 flags in PARALLEL,
   shuffle-min, no sleep. All global writes in a half-update come from
   wave 0, so tid-0's s_waitcnt(0) drains them before the flag store
   (same ordering discipline that passed rounds 8-10). */
__device__ __forceinline__ void fbar(unsigned* fl, int blk, unsigned target) {
  __syncthreads();
  if (threadIdx.x < 64) {
    if (threadIdx.x == 0) {
      __builtin_amdgcn_s_waitcnt(0);
      __hip_atomic_store(fl + blk * CSTRIDE, target,
                         __ATOMIC_RELAXED, __HIP_MEMORY_SCOPE_AGENT);
    }
    unsigned mn;
    do {
      unsigned v = 0xFFFFFFFFu;
      if (threadIdx.x < 32)
        v = (threadIdx.x == (unsigned)blk) ? target
            : uload(fl + threadIdx.x * CSTRIDE);
      mn = v;
#pragma unroll
      for (int o = 32; o; o >>= 1) {
        unsigned t = __shfl_xor(mn, o, 64);
        mn = t < mn ? t : mn;
      }
    } while (mn < target);
  }
  __syncthreads();
}

/* dir 0: rows=gts cols=preds (loss_2); dir 1: rows=preds cols=gts (loss_1). */
__global__ __launch_bounds__(256) void chamfer_k(const float* __restrict__ preds,
                                                 const float* __restrict__ gts,
                                                 float* __restrict__ ws) {
  __shared__ float4 colv[NPTS];
  int dir = blockIdx.x >> 5;
  int b = (blockIdx.x >> 3) & 3;
  int chunk = blockIdx.x & 7;
  const float* rowP = dir ? preds : gts;
  const float* colP = dir ? gts : preds;
  for (int c = threadIdx.x; c < NPTS; c += 256) {
    const float* p = colP + (b * NPTS + c) * 3;
    colv[c] = make_float4(p[0], p[1], p[2], p[0]*p[0] + p[1]*p[1] + p[2]*p[2]);
  }
  __syncthreads();
  int r = chunk * 256 + threadIdx.x;
  const float* p = rowP + (b * NPTS + r) * 3;
  float rn = p[0]*p[0] + p[1]*p[1] + p[2]*p[2];
  float nx = -2.f*p[0], ny = -2.f*p[1], nz = -2.f*p[2];
  float mn = 1e30f;
  for (int c = 0; c < NPTS; ++c) {
    float4 v = colv[c];
    float t = fmaf(nx, v.x, fmaf(ny, v.y, fmaf(nz, v.z, v.w)));
    mn = fminf(mn, t);
  }
  mn += rn;
  mn = wsum(mn);
  if ((threadIdx.x & 63) == 0) atomicAdd(ws + OFF_CHAM, mn * (1.0f/8192.0f));
}

/* One Sinkhorn half-update. Reduce-side scaled panel svL lives in LDS
   (staged once at kernel start); only the 8KB potential vector is staged
   per phase. oCw[o].w = -L2E*rn_o/eps encodes the output-side norm. */
__device__ __forceinline__ void half_update(const float4* __restrict__ svL,
    const float* __restrict__ potSrc, const float* __restrict__ oPts,
    const float4* __restrict__ oCw, const float* __restrict__ oPrev,
    float* __restrict__ oNew, float* __restrict__ errSlot,
    int blk, int tid, float* __restrict__ pot, float (*comb)[64]) {
  pot[tid]        = aload(potSrc + tid);
  pot[tid + 1024] = aload(potSrc + tid + 1024);
  __syncthreads();
  const int wave = tid >> 6, lane = tid & 63;
  const int ih = wave >> 3, jq = wave & 7;
  const int o0 = blk * 64 + jq * 8;
  float y0[8], y1[8], y2[8], S[8], s[8];
#pragma unroll
  for (int q = 0; q < 8; ++q) {
    int o = o0 + q;
    y0[q] = oPts[o*3+0]; y1[q] = oPts[o*3+1]; y2[q] = oPts[o*3+2];
    float c = LAC + oCw[o].w * LN2C;
    S[q] = L2E * (-aload(&oPrev[o]) - c);  /* base-2 shift from previous potential */
    s[q] = 0.f;
  }
  const float4* basep = svL + ih * 1024;
  const float* potp = pot + ih * 1024;
#pragma unroll 2
  for (int stp = 0; stp < 16; ++stp) {
    int il = stp * 64 + lane;
    float4 v = basep[il];
    float wv = fmaf(L2E, potp[il], v.w);
#pragma unroll
    for (int q = 0; q < 8; ++q) {
      float m = wv - S[q];
      m = fmaf(v.x, y0[q], m);
      m = fmaf(v.y, y1[q], m);
      m = fmaf(v.z, y2[q], m);
      s[q] += __builtin_amdgcn_exp2f(m);
    }
  }
#pragma unroll
  for (int q = 0; q < 8; ++q) s[q] = wsum(s[q]);
  if (lane == 0) {
#pragma unroll
    for (int q = 0; q < 8; ++q) comb[ih][jq * 8 + q] = s[q];
  }
  __syncthreads();
  if (tid < 64) {
    int o = blk * 64 + tid;
    float stot = fmaxf(comb[0][tid] + comb[1][tid], 1e-38f);
    float c = LAC + oCw[o].w * LN2C;
    float pv = aload(&oPrev[o]);
    float Sv = L2E * (-pv - c);
    float nv = -c - LN2C * (__builtin_amdgcn_logf(stot) + Sv);
    float d = fabsf(nv - pv);
    astore(&oNew[o], nv);
    d = wsum(d);
    if (tid == 0) atomicAdd(errSlot, d);
  }
  __syncthreads();
}

__global__ __launch_bounds__(1024, 4) void sink_k(const float* __restrict__ preds,
    const float* __restrict__ gts, float* __restrict__ ws, float* __restrict__ out) {
  __shared__ float4 svR[NPTS];   /* 32KB static reduce-panel (rows) */
  __shared__ float4 svC[NPTS];   /* 32KB static reduce-panel (cols) */
  __shared__ float pot[NPTS];    /* 8KB per-phase potential staging */
  __shared__ float comb[2][64];
  __shared__ int decS;
  const int p = blockIdx.x & 7;        /* 0-3 = C(gts,preds), 4-7 = C(preds,preds) */
  const int blk = blockIdx.x >> 3;     /* 0..31 */
  const int b = p & 3;
  const int g = p >> 2;
  const bool fs = (g == 0);
  const int tid = threadIdx.x;

  const float* colPts = preds + b * NPTS * 3;
  const float* rowPts = fs ? gts + b * NPTS * 3 : colPts;

  /* stage static scaled panels once: sv = (KS*x, KS*y, KS*z, -L2E*rn/eps) */
  for (int i = tid; i < NPTS; i += 1024) {
    const float* q3 = rowPts + i * 3;
    float x = q3[0], y = q3[1], z = q3[2];
    svR[i] = make_float4(KS*x, KS*y, KS*z, -L2E*INV_EPS*(x*x + y*y + z*z));
    const float* c3 = colPts + i * 3;
    float cx = c3[0], cy = c3[1], cz = c3[2];
    svC[i] = make_float4(KS*cx, KS*cy, KS*cz, -L2E*INV_EPS*(cx*cx + cy*cy + cz*cz));
  }

  float* Abase = ws + OFF_A;           /* A[w] at Abase + w*16384 + p*2048 */
  float* Bbase = ws + OFF_B;
  float* err = ws + OFF_ERR;
  unsigned* ub = reinterpret_cast<unsigned*>(ws);
  unsigned* flags = ub + OFF_FLAG;               /* flags[p][blk] stride CSTRIDE */
  unsigned* myfl = flags + p * 32 * CSTRIDE;
  unsigned* done = ub + OFF_DONE;
  const float sc = EPSC / (float)NPTS;

  int last = NITS - 1;
  /* it == NITS executes the gate only (post-loop boundary check). */
  for (int it = 0; it <= NITS; ++it) {
    const int w = it & 1, r = 1 - (it & 1);
    /* Gate: resolve D(it-1) = reference cond on err[it-2]. Wave-parallel
       min over the group's 4x32 flags >= 2it-2 (one iteration of slack --
       normally zero wait). Deterministic: final gated values only. */
    if (it >= 2) {
      if (tid < 64) {
        unsigned need = 2u * (unsigned)it - 2u;
        const unsigned* gfl = flags + g * 128 * CSTRIDE;
        for (;;) {
          unsigned v0 = uload(gfl + tid * CSTRIDE);
          unsigned v1 = uload(gfl + (64 + tid) * CSTRIDE);
          unsigned mn = v0 < v1 ? v0 : v1;
#pragma unroll
          for (int o = 32; o; o >>= 1) {
            unsigned t = __shfl_xor(mn, o, 64);
            mn = t < mn ? t : mn;
          }
          if (mn >= need) break;
          __builtin_amdgcn_s_sleep(2);
        }
        if (tid == 0) {
          int j = it - 2;
          float ae = 0.f, be = 0.f;
#pragma unroll
          for (int q = 0; q < 4; ++q) {
            ae = fmaxf(ae, aload(err + ((j*8 + g*4 + q)*2 + 0)));
            be = fmaxf(be, aload(err + ((j*8 + g*4 + q)*2 + 1)));
          }
          decS = ((sc*ae >= TOLC) || (sc*be >= TOLC)) ? 1 : 0;
        }
      }
      __syncthreads();
      if (decS == 0) { last = it - 2; break; }  /* it-1 speculative: parity rollback */
    }
    if (it == NITS) { last = NITS - 1; break; }
    /* A-half: reduce over rows (pot = B[r]), outputs = columns, write A[w] */
    half_update(svR, Bbase + r*16384 + p*NPTS, colPts, svC,
                Abase + r*16384 + p*NPTS, Abase + w*16384 + p*NPTS,
                err + ((it*8 + p)*2 + 0), blk, tid, pot, comb);
    fbar(myfl, blk, 2u*(unsigned)it + 1u);
    /* B-half: reduce over cols (pot = fresh A[w]), outputs = rows, write B[w] */
    half_update(svC, Abase + w*16384 + p*NPTS, rowPts, svR,
                Bbase + r*16384 + p*NPTS, Bbase + w*16384 + p*NPTS,
                err + ((it*8 + p)*2 + 1), blk, tid, pot, comb);
    fbar(myfl, blk, 2u*(unsigned)it + 2u);
    last = it;
  }

  /* cost = sum_ij exp(A_j + B_i - C/eps) * C_ij, from parity (last&1) */
  {
    const float* Af = Abase + (last & 1)*16384 + p*NPTS;
    const float* Bf = Bbase + (last & 1)*16384 + p*NPTS;
    pot[tid]        = aload(Bf + tid);
    pot[tid + 1024] = aload(Bf + tid + 1024);
    __syncthreads();
    const int wave = tid >> 6, lane = tid & 63;
    const int ih = wave >> 3, jq = wave & 7;
    const int j0 = blk * 64 + jq * 8;
    float y0[8], y1[8], y2[8], Q[8], EA[8];
#pragma unroll
    for (int q = 0; q < 8; ++q) {
      int j = j0 + q;
      y0[q] = colPts[j*3+0]; y1[q] = colPts[j*3+1]; y2[q] = colPts[j*3+2];
      float aj = aload(Af + j);
      Q[q] = L2E * aj + svC[j].w;   /* = L2E*(aj - rn_j/eps) */
      EA[q] = EPSC * aj;
    }
    float acc = 0.f;
    const float4* basep = svR + ih * 1024;
    const float* potp = pot + ih * 1024;
#pragma unroll 2
    for (int stp = 0; stp < 16; ++stp) {
      int il = stp * 64 + lane;
      float4 v = basep[il];
      float pw = potp[il];
      float wv = fmaf(L2E, pw, v.w);
      float eb = EPSC * pw;
#pragma unroll
      for (int q = 0; q < 8; ++q) {
        float m = wv + Q[q];
        m = fmaf(v.x, y0[q], m);
        m = fmaf(v.y, y1[q], m);
        m = fmaf(v.z, y2[q], m);
        float e = __builtin_amdgcn_exp2f(m);           /* transp * (n*m) */
        float Cv = fmaf(-(EPSC*LN2C), m, eb + EA[q]);  /* C = eps*(A+B - m*ln2) */
        acc = fmaf(e, Cv, acc);
      }
    }
    acc = wsum(acc);
    if (lane == 0) atomicAdd(ws + OFF_COST + p, acc);
  }

  /* done: drain cost adds, arrive; block 0 assembles outputs */
  __syncthreads();
  if (tid == 0) {
    __builtin_amdgcn_s_waitcnt(0);
    __hip_atomic_fetch_add(done, 1u, __ATOMIC_RELAXED, __HIP_MEMORY_SCOPE_AGENT);
  }
  if (blockIdx.x == 0) {
    if (tid == 0) {
      while (__hip_atomic_load(done, __ATOMIC_RELAXED, __HIP_MEMORY_SCOPE_AGENT) < 256u)
        __builtin_amdgcn_s_sleep(1);
    }
    __syncthreads();
    if (tid < 4)
      out[tid] = (aload(ws + OFF_COST + tid) - 0.5f * aload(ws + OFF_COST + 4 + tid)) *
                 (1.0f / ((float)NPTS * (float)NPTS));
    if (tid == 4) out[4] = aload(ws + OFF_CHAM);
  }
}

extern "C" void kernel_launch(void* const* d_in, const int* in_sizes, int n_in,
                              void* d_out, int out_size, void* d_ws, size_t ws_size,
                              hipStream_t stream) {
  const float* preds = (const float*)d_in[0];
  const float* gts   = (const float*)d_in[1];
  float* wsf  = (float*)d_ws;
  float* outf = (float*)d_out;

  hipMemsetAsync(d_ws, 0, ZERO_FLOATS * sizeof(float), stream);
  chamfer_k<<<64, 256, 0, stream>>>(preds, gts, wsf);

  void* args[] = { (void*)&preds, (void*)&gts, (void*)&wsf, (void*)&outf };
  hipLaunchCooperativeKernel((void*)sink_k, dim3(256), dim3(1024), args, 0, stream);
}